// Round 7
// baseline (1277.521 us; speedup 1.0000x reference)
//
#include <hip/hip_runtime.h>
#include <hip/hip_bf16.h>

// ---- problem constants ----
#define E_NUM 16
#define TOPK 4
#define H_DIM 2048
#define I_DIM 1408
#define IS_DIM 5632
#define M_TOK 4096

typedef __attribute__((ext_vector_type(8))) short short8;
typedef __attribute__((ext_vector_type(4))) float f32x4;

static __device__ __forceinline__ unsigned short f2bf(float f) {
    unsigned int u = __float_as_uint(f);
    unsigned int r = (u + 0x7FFFu + ((u >> 16) & 1u)) >> 16;
    return (unsigned short)r;
}

static __device__ __forceinline__ void gl16(const unsigned short* g, unsigned short* l) {
    __builtin_amdgcn_global_load_lds(
        (const __attribute__((address_space(1))) unsigned int*)g,
        (__attribute__((address_space(3))) unsigned int*)l, 16, 0, 0);
}

// ---------------- router: fp32 logits, softmax, top-4, shared gate ----------------
__global__ __launch_bounds__(256) void k_router(
    const float* __restrict__ x, const float* __restrict__ gw,
    const float* __restrict__ sgw, int* __restrict__ counts,
    int* __restrict__ ltok, float* __restrict__ lcoef, float* __restrict__ sg)
{
    const int wid = threadIdx.x >> 6, lane = threadIdx.x & 63;
    const int t = blockIdx.x * 4 + wid;
    const float* xr = x + (size_t)t * H_DIM;
    float xv[32];
#pragma unroll
    for (int i = 0; i < 32; ++i) xv[i] = xr[i * 64 + lane];

    float lg[E_NUM];
    for (int e = 0; e < E_NUM; ++e) {
        const float* g = gw + (size_t)e * H_DIM;
        float s = 0.f;
#pragma unroll
        for (int i = 0; i < 32; ++i) s += xv[i] * g[i * 64 + lane];
#pragma unroll
        for (int off = 32; off; off >>= 1) s += __shfl_xor(s, off);
        lg[e] = s;
    }
    {
        float s = 0.f;
#pragma unroll
        for (int i = 0; i < 32; ++i) s += xv[i] * sgw[i * 64 + lane];
#pragma unroll
        for (int off = 32; off; off >>= 1) s += __shfl_xor(s, off);
        if (lane == 0) sg[t] = 1.f / (1.f + __expf(-s));
    }
    float mx = lg[0];
#pragma unroll
    for (int e = 1; e < E_NUM; ++e) mx = fmaxf(mx, lg[e]);
    float sum = 0.f, w[E_NUM];
#pragma unroll
    for (int e = 0; e < E_NUM; ++e) { w[e] = __expf(lg[e] - mx); sum += w[e]; }
    float inv = 1.f / sum;
#pragma unroll
    for (int e = 0; e < E_NUM; ++e) w[e] *= inv;

    if (lane == 0) {
        for (int j = 0; j < TOPK; ++j) {
            float best = -1.f; int bi = 0;
            for (int e = 0; e < E_NUM; ++e) if (w[e] > best) { best = w[e]; bi = e; }
            int pos = atomicAdd(&counts[bi], 1);
            ltok[bi * M_TOK + pos]  = t;
            lcoef[bi * M_TOK + pos] = best;
            w[bi] = -2.f;
        }
    }
}

__global__ void k_prefix(const int* __restrict__ counts, int* __restrict__ base) {
    if (threadIdx.x == 0) {
        int a = 0;
        for (int e = 0; e < E_NUM; ++e) { base[e] = a; a += counts[e]; }
        base[E_NUM] = a;
    }
}

// ---------------- fp32 -> bf16 conversion (grid-stride) ----------------
__global__ __launch_bounds__(256) void k_cvtw(const float* __restrict__ src,
                                              unsigned short* __restrict__ dst, size_t n8)
{
    size_t stride = (size_t)gridDim.x * 256;
    for (size_t t = (size_t)blockIdx.x * 256 + threadIdx.x; t < n8; t += stride) {
        size_t i = t * 8;
        float4 a = *(const float4*)(src + i);
        float4 b = *(const float4*)(src + i + 4);
        union { unsigned short u[8]; short8 v; } o;
        o.u[0] = f2bf(a.x); o.u[1] = f2bf(a.y); o.u[2] = f2bf(a.z); o.u[3] = f2bf(a.w);
        o.u[4] = f2bf(b.x); o.u[5] = f2bf(b.y); o.u[6] = f2bf(b.z); o.u[7] = f2bf(b.w);
        *(short8*)(dst + i) = o.v;
    }
}

// fp32 -> bf16 with gate/up 16-row-chunk interleave within TWOI-row groups.
// dst row pr: chunk q=pr>>4 even -> gate row (q>>1)*16+(pr&15); odd -> +NOFF.
// Row length fixed at H_DIM=2048.
template<int TWOI, int NOFF>
__global__ __launch_bounds__(256) void k_cvtp(const float* __restrict__ src,
                                              unsigned short* __restrict__ dst, size_t n8)
{
    size_t stride = (size_t)gridDim.x * 256;
    for (size_t t = (size_t)blockIdx.x * 256 + threadIdx.x; t < n8; t += stride) {
        size_t i = t * 8;
        unsigned drow = (unsigned)(i >> 11);
        unsigned col  = (unsigned)(i & 2047u);
        unsigned grp = drow / (unsigned)TWOI;
        unsigned rr  = drow - grp * (unsigned)TWOI;
        unsigned q = rr >> 4, rm = rr & 15u;
        unsigned srow = ((q >> 1) << 4) + rm + ((q & 1u) ? (unsigned)NOFF : 0u);
        const float* s = src + (((size_t)grp * TWOI + srow) << 11) + col;
        float4 a = *(const float4*)s;
        float4 b = *(const float4*)(s + 4);
        union { unsigned short u[8]; short8 v; } o;
        o.u[0] = f2bf(a.x); o.u[1] = f2bf(a.y); o.u[2] = f2bf(a.z); o.u[3] = f2bf(a.w);
        o.u[4] = f2bf(b.x); o.u[5] = f2bf(b.y); o.u[6] = f2bf(b.z); o.u[7] = f2bf(b.w);
        *(short8*)(dst + i) = o.v;
    }
}

// ---------------- 256x256 phase-split dbuf bf16 MFMA GEMM ----------------
// Same data path as round 6 (cvtp-interleaved gate/up, paired silu epilogue).
// SAFE schedule (round-3 hazard structure): phases read buf cur, stage-issue
// into buf nxt, NO intra-tile barriers; one lgkmcnt(0)+vmcnt(0)+barrier per
// K-tile. Per-phase MFMA clusters wrapped in setprio.
template<int MODE, int KDIM, long long BSTR, int KSPLIT>
__global__ __launch_bounds__(512, 2) void k_gemm(
    const unsigned short* __restrict__ Abase,
    const unsigned short* __restrict__ Bbase,
    void* __restrict__ outp,
    const int* __restrict__ ltok, const float* __restrict__ lcoef,
    const int* __restrict__ counts, const int* __restrict__ basearr,
    const float* __restrict__ sg)
{
    constexpr bool UP = (MODE == 0 || MODE == 2);
    constexpr int OSTR = (MODE == 0) ? IS_DIM : I_DIM;   // h row stride (UP only)
    constexpr int KCH = KDIM / KSPLIT;
    constexpr int NT = KCH / 64;

    extern __shared__ unsigned short smem[];
    unsigned short* sA = smem;            // [2 buf][256 rows][64]
    unsigned short* sB = smem + 32768;    // [2 buf][256 rows][64]

    const int tid = threadIdx.x;
    const int lane = tid & 63, wid = tid >> 6;
    const int wr = wid >> 2, wcol = wid & 3;
    const int lr = lane & 15, lk = lane >> 4;

    // ---- bijective XCD-chunk swizzle over (x,y), y-major within chunk ----
    const unsigned gx = gridDim.x, gy = gridDim.y;
    const unsigned nwg = gx * gy;
    const unsigned orig = blockIdx.y * gx + blockIdx.x;
    const unsigned q8 = nwg >> 3, r8 = nwg & 7;
    const unsigned xcd = orig & 7, off8 = orig >> 3;
    const unsigned wg = ((xcd < r8) ? xcd * (q8 + 1) : r8 * (q8 + 1) + (xcd - r8) * q8) + off8;
    const int n0 = (int)(wg / gy) * 256;
    const int r0 = (int)(wg % gy) * 256;
    const int e  = blockIdx.z;

    int cnt = M_TOK, gbase = 0;
    if constexpr (MODE == 2 || MODE == 3) {
        cnt = counts[e];
        if (r0 >= cnt) return;
        gbase = basearr[e];
    }
    const int kbeg = (KSPLIT > 1) ? e * KCH : 0;
    const unsigned short* Bexp = Bbase + (size_t)e * (size_t)BSTR;

    // ---- staging source pointers: [half][i], pre-swizzled, fixed across K ----
    const unsigned short* aptr[2][2];
    const unsigned short* bptr[2][2];
#pragma unroll
    for (int h = 0; h < 2; ++h) {
#pragma unroll
        for (int i = 0; i < 2; ++i) {
            const int eo = (i * 512 + tid) * 8;        // elem offset in half [0,8192)
            const int prow = eo >> 6;                  // 0..127
            const int kch = ((eo >> 3) & 7) ^ (prow & 7);
            const int lrow = h * 128 + prow;
            int ar;
            if constexpr (MODE == 0 || MODE == 1) ar = r0 + lrow;
            else {
                int rr2 = r0 + lrow; if (rr2 > cnt - 1) rr2 = cnt - 1;
                ar = (MODE == 2) ? ltok[e * M_TOK + rr2] : (gbase + rr2);
            }
            aptr[h][i] = Abase + (size_t)ar * KDIM + kbeg + kch * 8;
            bptr[h][i] = Bexp + (size_t)(n0 + lrow) * KDIM + kbeg + kch * 8;
        }
    }

    f32x4 acc[8][4];
    const f32x4 z = {0.f, 0.f, 0.f, 0.f};
#pragma unroll
    for (int m = 0; m < 8; ++m)
#pragma unroll
        for (int n = 0; n < 4; ++n) acc[m][n] = z;

    auto STAGEA = [&](int h, int buf, int kt) {
#pragma unroll
        for (int i = 0; i < 2; ++i)
            gl16(aptr[h][i] + kt, &sA[buf * 16384 + h * 8192 + (i * 512 + tid) * 8]);
    };
    auto STAGEB = [&](int h, int buf, int kt) {
#pragma unroll
        for (int i = 0; i < 2; ++i)
            gl16(bptr[h][i] + kt, &sB[buf * 16384 + h * 8192 + (i * 512 + tid) * 8]);
    };

    // prologue: full tile 0 into buf 0, drain
    STAGEA(0, 0, 0); STAGEB(0, 0, 0); STAGEB(1, 0, 0); STAGEA(1, 0, 0);
    asm volatile("s_waitcnt vmcnt(0)" ::: "memory");
    __builtin_amdgcn_s_barrier();

    short8 af[8], bfA[4], bfB[4];

#pragma unroll 1
    for (int t = 0; t < NT; ++t) {
        const int cur = t & 1, nxt = cur ^ 1;
        const int kt1 = (t + 1) * 64;
        const bool pf = (t + 1 < NT);
        const int cb = cur * 16384;

        // ---------- P1: (mh0, nh0) ----------
#pragma unroll
        for (int m = 0; m < 4; ++m) {
            const int row = wr * 64 + m * 16 + lr;
#pragma unroll
            for (int kk = 0; kk < 2; ++kk)
                af[m * 2 + kk] = *(const short8*)&sA[cb + (row << 6) + ((((kk << 2) + lk) ^ (row & 7)) << 3)];
        }
#pragma unroll
        for (int n = 0; n < 2; ++n) {
            const int row = wcol * 32 + n * 16 + lr;
#pragma unroll
            for (int kk = 0; kk < 2; ++kk)
                bfA[n * 2 + kk] = *(const short8*)&sB[cb + (row << 6) + ((((kk << 2) + lk) ^ (row & 7)) << 3)];
        }
        if (pf) STAGEA(0, nxt, kt1);
        __builtin_amdgcn_s_setprio(1);
#pragma unroll
        for (int kk = 0; kk < 2; ++kk)
#pragma unroll
            for (int n = 0; n < 2; ++n)
#pragma unroll
                for (int m = 0; m < 4; ++m)
                    acc[m][n] = __builtin_amdgcn_mfma_f32_16x16x32_bf16(af[m * 2 + kk], bfA[n * 2 + kk], acc[m][n], 0, 0, 0);
        __builtin_amdgcn_s_setprio(0);

        // ---------- P2: (mh0, nh1) ----------
#pragma unroll
        for (int n = 0; n < 2; ++n) {
            const int row = 128 + wcol * 32 + n * 16 + lr;
#pragma unroll
            for (int kk = 0; kk < 2; ++kk)
                bfB[n * 2 + kk] = *(const short8*)&sB[cb + (row << 6) + ((((kk << 2) + lk) ^ (row & 7)) << 3)];
        }
        if (pf) STAGEB(0, nxt, kt1);
        __builtin_amdgcn_s_setprio(1);
#pragma unroll
        for (int kk = 0; kk < 2; ++kk)
#pragma unroll
            for (int n = 0; n < 2; ++n)
#pragma unroll
                for (int m = 0; m < 4; ++m)
                    acc[m][n + 2] = __builtin_amdgcn_mfma_f32_16x16x32_bf16(af[m * 2 + kk], bfB[n * 2 + kk], acc[m][n + 2], 0, 0, 0);
        __builtin_amdgcn_s_setprio(0);

        // ---------- P3: (mh1, nh0) ----------
#pragma unroll
        for (int m = 0; m < 4; ++m) {
            const int row = 128 + wr * 64 + m * 16 + lr;
#pragma unroll
            for (int kk = 0; kk < 2; ++kk)
                af[m * 2 + kk] = *(const short8*)&sA[cb + (row << 6) + ((((kk << 2) + lk) ^ (row & 7)) << 3)];
        }
        if (pf) STAGEB(1, nxt, kt1);
        __builtin_amdgcn_s_setprio(1);
#pragma unroll
        for (int kk = 0; kk < 2; ++kk)
#pragma unroll
            for (int n = 0; n < 2; ++n)
#pragma unroll
                for (int m = 0; m < 4; ++m)
                    acc[m + 4][n] = __builtin_amdgcn_mfma_f32_16x16x32_bf16(af[m * 2 + kk], bfA[n * 2 + kk], acc[m + 4][n], 0, 0, 0);
        __builtin_amdgcn_s_setprio(0);

        // ---------- P4: (mh1, nh1) ----------
        if (pf) STAGEA(1, nxt, kt1);
        __builtin_amdgcn_s_setprio(1);
#pragma unroll
        for (int kk = 0; kk < 2; ++kk)
#pragma unroll
            for (int n = 0; n < 2; ++n)
#pragma unroll
                for (int m = 0; m < 4; ++m)
                    acc[m + 4][n + 2] = __builtin_amdgcn_mfma_f32_16x16x32_bf16(af[m * 2 + kk], bfB[n * 2 + kk], acc[m + 4][n + 2], 0, 0, 0);
        __builtin_amdgcn_s_setprio(0);

        // ---------- tile end: full drain + barrier (round-3 semantics) ----------
        asm volatile("s_waitcnt lgkmcnt(0)" ::: "memory");
        asm volatile("s_waitcnt vmcnt(0)" ::: "memory");
        __builtin_amdgcn_s_barrier();
    }

    // ---- epilogue ----
    if constexpr (UP) {
        const int hc0 = (n0 >> 1) + wcol * 16 + lr;
        unsigned short* hb = (unsigned short*)outp;
#pragma unroll
        for (int m = 0; m < 8; ++m) {
            const int rb = (m < 4 ? wr * 64 + m * 16 : 128 + wr * 64 + (m - 4) * 16) + lk * 4;
#pragma unroll
            for (int j = 0; j < 4; ++j) {
                const int r = rb + j;
                bool ok; size_t orow;
                if constexpr (MODE == 0) { ok = true; orow = (size_t)(r0 + r) * OSTR; }
                else { ok = (r0 + r < cnt); orow = (size_t)(gbase + r0 + r) * OSTR; }
                if (ok) {
                    float g0 = acc[m][0][j], u0 = acc[m][1][j];
                    float g1 = acc[m][2][j], u1 = acc[m][3][j];
                    hb[orow + hc0]      = f2bf(g0 / (1.f + __expf(-g0)) * u0);
                    hb[orow + hc0 + 64] = f2bf(g1 / (1.f + __expf(-g1)) * u1);
                }
            }
        }
    } else {
        float* op = (float*)outp;
#pragma unroll
        for (int m = 0; m < 8; ++m) {
            const int rb = (m < 4 ? wr * 64 + m * 16 : 128 + wr * 64 + (m - 4) * 16) + lk * 4;
#pragma unroll
            for (int j = 0; j < 4; ++j) {
                const int r = rb + j;
                int tok; float scale; bool ok;
                if constexpr (MODE == 1) {
                    tok = r0 + r; scale = sg[tok]; ok = true;
                } else {
                    ok = (r0 + r < cnt);
                    int idx = ok ? (e * M_TOK + r0 + r) : (e * M_TOK);
                    tok = ltok[idx]; scale = lcoef[idx];
                }
                if (ok) {
                    size_t orow = (size_t)tok * H_DIM;
#pragma unroll
                    for (int n = 0; n < 4; ++n) {
                        const int col = n0 + (n < 2 ? wcol * 32 + n * 16 : 128 + wcol * 32 + (n - 2) * 16) + lr;
                        atomicAdd(op + orow + col, acc[m][n][j] * scale);
                    }
                }
            }
        }
    }
}

extern "C" void kernel_launch(void* const* d_in, const int* in_sizes, int n_in,
                              void* d_out, int out_size, void* d_ws, size_t ws_size,
                              hipStream_t stream) {
    const float* x    = (const float*)d_in[0];
    const float* gw   = (const float*)d_in[1];
    const float* sgw  = (const float*)d_in[2];
    const float* w13  = (const float*)d_in[3];
    const float* w2   = (const float*)d_in[4];
    const float* sguw = (const float*)d_in[5];
    const float* sdw  = (const float*)d_in[6];
    float* out = (float*)d_out;

    char* ws = (char*)d_ws;
    unsigned short* xb    = (unsigned short*)ws;                // 16,777,216 B
    unsigned short* hbuf  = (unsigned short*)(ws + 16777216);   // 46,137,344 B (hs then he)
    unsigned short* w13b  = (unsigned short*)(ws + 62914560);   // 184,549,376 B (permuted)
    unsigned short* w2b   = (unsigned short*)(ws + 247463936);  //  92,274,688 B
    unsigned short* sguwb = (unsigned short*)(ws + 339738624);  //  46,137,344 B (permuted)
    unsigned short* sdwb  = (unsigned short*)(ws + 385875968);  //  23,068,672 B
    size_t so = 408944640ULL;
    int*   ltok   = (int*)  (ws + so);
    float* lcoef  = (float*)(ws + so + 262144);
    int*   counts = (int*)  (ws + so + 524288);
    int*   basep  = (int*)  (ws + so + 524288 + 256);
    float* sg     = (float*)(ws + so + 524288 + 512);

    hipMemsetAsync(counts, 0, 64, stream);
    hipMemsetAsync(out, 0, (size_t)out_size * sizeof(float), stream);
    k_router<<<M_TOK / 4, 256, 0, stream>>>(x, gw, sgw, counts, ltok, lcoef, sg);
    k_prefix<<<1, 64, 0, stream>>>(counts, basep);
    k_cvtw<<<4096, 256, 0, stream>>>(x, xb, (size_t)M_TOK * H_DIM / 8);
    k_cvtp<2 * IS_DIM, IS_DIM><<<8192, 256, 0, stream>>>(sguw, sguwb, (size_t)2 * IS_DIM * H_DIM / 8);
    k_cvtw<<<8192, 256, 0, stream>>>(sdw,  sdwb,  (size_t)H_DIM * IS_DIM / 8);
    k_cvtp<2 * I_DIM, I_DIM><<<8192, 256, 0, stream>>>(w13, w13b, (size_t)E_NUM * 2 * I_DIM * H_DIM / 8);
    k_cvtw<<<8192, 256, 0, stream>>>(w2,   w2b,   (size_t)E_NUM * H_DIM * I_DIM / 8);

    static const int DYN = 131072;
    (void)hipFuncSetAttribute(reinterpret_cast<const void*>(&k_gemm<0, 2048, 0LL, 1>),
                              hipFuncAttributeMaxDynamicSharedMemorySize, DYN);
    (void)hipFuncSetAttribute(reinterpret_cast<const void*>(&k_gemm<1, 5632, 0LL, 2>),
                              hipFuncAttributeMaxDynamicSharedMemorySize, DYN);
    (void)hipFuncSetAttribute(reinterpret_cast<const void*>(&k_gemm<2, 2048, 5767168LL, 1>),
                              hipFuncAttributeMaxDynamicSharedMemorySize, DYN);
    (void)hipFuncSetAttribute(reinterpret_cast<const void*>(&k_gemm<3, 1408, 2883584LL, 1>),
                              hipFuncAttributeMaxDynamicSharedMemorySize, DYN);

    // shared up: xb[4096,2048] x sguwb^T -> silu-mul pairs -> hs bf16 [4096,5632]
    k_gemm<0, 2048, 0LL, 1>
        <<<dim3(2 * IS_DIM / 256, M_TOK / 256, 1), 512, DYN, stream>>>(
            xb, sguwb, hbuf, ltok, lcoef, counts, basep, sg);
    // shared down (split-K=2): hs x sdwb^T * sg -> atomicAdd out
    k_gemm<1, 5632, 0LL, 2>
        <<<dim3(H_DIM / 256, M_TOK / 256, 2), 512, DYN, stream>>>(
            hbuf, sdwb, out, ltok, lcoef, counts, basep, sg);
    // expert up (gathered): xb x w13b_e^T -> silu-mul -> he bf16 [16384,1408]
    k_gemm<2, 2048, 5767168LL, 1>
        <<<dim3(2 * I_DIM / 256, M_TOK / 256, E_NUM), 512, DYN, stream>>>(
            xb, w13b, hbuf, ltok, lcoef, counts, basep, sg);
    // expert down: he x w2b_e^T * coef -> atomicAdd out
    k_gemm<3, 1408, 2883584LL, 1>
        <<<dim3(H_DIM / 256, M_TOK / 256, E_NUM), 512, DYN, stream>>>(
            hbuf, w2b, out, ltok, lcoef, counts, basep, sg);
}

// Round 8
// 1253.327 us; speedup vs baseline: 1.0193x; 1.0193x over previous
//
#include <hip/hip_runtime.h>
#include <hip/hip_bf16.h>

// ---- problem constants ----
#define E_NUM 16
#define TOPK 4
#define H_DIM 2048
#define I_DIM 1408
#define IS_DIM 5632
#define M_TOK 4096

typedef __attribute__((ext_vector_type(8))) short short8;
typedef __attribute__((ext_vector_type(4))) float f32x4;

static __device__ __forceinline__ unsigned short f2bf(float f) {
    unsigned int u = __float_as_uint(f);
    unsigned int r = (u + 0x7FFFu + ((u >> 16) & 1u)) >> 16;
    return (unsigned short)r;
}

static __device__ __forceinline__ void gl16(const unsigned short* g, unsigned short* l) {
    __builtin_amdgcn_global_load_lds(
        (const __attribute__((address_space(1))) unsigned int*)g,
        (__attribute__((address_space(3))) unsigned int*)l, 16, 0, 0);
}

// ---------------- router: fp32 logits, softmax, top-4, shared gate ----------------
__global__ __launch_bounds__(256) void k_router(
    const float* __restrict__ x, const float* __restrict__ gw,
    const float* __restrict__ sgw, int* __restrict__ counts,
    int* __restrict__ ltok, float* __restrict__ lcoef, float* __restrict__ sg)
{
    const int wid = threadIdx.x >> 6, lane = threadIdx.x & 63;
    const int t = blockIdx.x * 4 + wid;
    const float* xr = x + (size_t)t * H_DIM;
    float xv[32];
#pragma unroll
    for (int i = 0; i < 32; ++i) xv[i] = xr[i * 64 + lane];

    float lg[E_NUM];
    for (int e = 0; e < E_NUM; ++e) {
        const float* g = gw + (size_t)e * H_DIM;
        float s = 0.f;
#pragma unroll
        for (int i = 0; i < 32; ++i) s += xv[i] * g[i * 64 + lane];
#pragma unroll
        for (int off = 32; off; off >>= 1) s += __shfl_xor(s, off);
        lg[e] = s;
    }
    {
        float s = 0.f;
#pragma unroll
        for (int i = 0; i < 32; ++i) s += xv[i] * sgw[i * 64 + lane];
#pragma unroll
        for (int off = 32; off; off >>= 1) s += __shfl_xor(s, off);
        if (lane == 0) sg[t] = 1.f / (1.f + __expf(-s));
    }
    float mx = lg[0];
#pragma unroll
    for (int e = 1; e < E_NUM; ++e) mx = fmaxf(mx, lg[e]);
    float sum = 0.f, w[E_NUM];
#pragma unroll
    for (int e = 0; e < E_NUM; ++e) { w[e] = __expf(lg[e] - mx); sum += w[e]; }
    float inv = 1.f / sum;
#pragma unroll
    for (int e = 0; e < E_NUM; ++e) w[e] *= inv;

    if (lane == 0) {
        for (int j = 0; j < TOPK; ++j) {
            float best = -1.f; int bi = 0;
            for (int e = 0; e < E_NUM; ++e) if (w[e] > best) { best = w[e]; bi = e; }
            int pos = atomicAdd(&counts[bi], 1);
            ltok[bi * M_TOK + pos]  = t;
            lcoef[bi * M_TOK + pos] = best;
            w[bi] = -2.f;
        }
    }
}

__global__ void k_prefix(const int* __restrict__ counts, int* __restrict__ base) {
    if (threadIdx.x == 0) {
        int a = 0;
        for (int e = 0; e < E_NUM; ++e) { base[e] = a; a += counts[e]; }
        base[E_NUM] = a;
    }
}

// ---------------- fp32 -> bf16 conversion (grid-stride) ----------------
__global__ __launch_bounds__(256) void k_cvtw(const float* __restrict__ src,
                                              unsigned short* __restrict__ dst, size_t n8)
{
    size_t stride = (size_t)gridDim.x * 256;
    for (size_t t = (size_t)blockIdx.x * 256 + threadIdx.x; t < n8; t += stride) {
        size_t i = t * 8;
        float4 a = *(const float4*)(src + i);
        float4 b = *(const float4*)(src + i + 4);
        union { unsigned short u[8]; short8 v; } o;
        o.u[0] = f2bf(a.x); o.u[1] = f2bf(a.y); o.u[2] = f2bf(a.z); o.u[3] = f2bf(a.w);
        o.u[4] = f2bf(b.x); o.u[5] = f2bf(b.y); o.u[6] = f2bf(b.z); o.u[7] = f2bf(b.w);
        *(short8*)(dst + i) = o.v;
    }
}

// fp32 -> bf16 with gate/up 16-row-chunk interleave within TWOI-row groups.
// dst row pr: chunk q=pr>>4 even -> gate row (q>>1)*16+(pr&15); odd -> +NOFF.
// Row length fixed at H_DIM=2048.
template<int TWOI, int NOFF>
__global__ __launch_bounds__(256) void k_cvtp(const float* __restrict__ src,
                                              unsigned short* __restrict__ dst, size_t n8)
{
    size_t stride = (size_t)gridDim.x * 256;
    for (size_t t = (size_t)blockIdx.x * 256 + threadIdx.x; t < n8; t += stride) {
        size_t i = t * 8;
        unsigned drow = (unsigned)(i >> 11);
        unsigned col  = (unsigned)(i & 2047u);
        unsigned grp = drow / (unsigned)TWOI;
        unsigned rr  = drow - grp * (unsigned)TWOI;
        unsigned q = rr >> 4, rm = rr & 15u;
        unsigned srow = ((q >> 1) << 4) + rm + ((q & 1u) ? (unsigned)NOFF : 0u);
        const float* s = src + (((size_t)grp * TWOI + srow) << 11) + col;
        float4 a = *(const float4*)s;
        float4 b = *(const float4*)(s + 4);
        union { unsigned short u[8]; short8 v; } o;
        o.u[0] = f2bf(a.x); o.u[1] = f2bf(a.y); o.u[2] = f2bf(a.z); o.u[3] = f2bf(a.w);
        o.u[4] = f2bf(b.x); o.u[5] = f2bf(b.y); o.u[6] = f2bf(b.z); o.u[7] = f2bf(b.w);
        *(short8*)(dst + i) = o.v;
    }
}

// ---------------- 256x256 8-phase pipelined bf16 MFMA GEMM ----------------
// Counted-vmcnt schedule (round 6) + last-tile epilogue drains (the fix):
// steady state: vmcnt(4) at P1/P2/P4 ends; last tile (pf=false):
// P1 end vmcnt(2) [drain B-hi(last)], P2 end vmcnt(0) [drain A-hi(last)].
template<int MODE, int KDIM, long long BSTR, int KSPLIT>
__global__ __launch_bounds__(512, 2) void k_gemm(
    const unsigned short* __restrict__ Abase,
    const unsigned short* __restrict__ Bbase,
    void* __restrict__ outp,
    const int* __restrict__ ltok, const float* __restrict__ lcoef,
    const int* __restrict__ counts, const int* __restrict__ basearr,
    const float* __restrict__ sg)
{
    constexpr bool UP = (MODE == 0 || MODE == 2);
    constexpr int OSTR = (MODE == 0) ? IS_DIM : I_DIM;   // h row stride (UP only)
    constexpr int KCH = KDIM / KSPLIT;
    constexpr int NT = KCH / 64;

    extern __shared__ unsigned short smem[];
    unsigned short* sA = smem;            // [2 buf][256 rows][64]
    unsigned short* sB = smem + 32768;    // [2 buf][256 rows][64]

    const int tid = threadIdx.x;
    const int lane = tid & 63, wid = tid >> 6;
    const int wr = wid >> 2, wcol = wid & 3;
    const int lr = lane & 15, lk = lane >> 4;

    // ---- bijective XCD-chunk swizzle over (x,y), y-major within chunk ----
    const unsigned gx = gridDim.x, gy = gridDim.y;
    const unsigned nwg = gx * gy;
    const unsigned orig = blockIdx.y * gx + blockIdx.x;
    const unsigned q8 = nwg >> 3, r8 = nwg & 7;
    const unsigned xcd = orig & 7, off8 = orig >> 3;
    const unsigned wg = ((xcd < r8) ? xcd * (q8 + 1) : r8 * (q8 + 1) + (xcd - r8) * q8) + off8;
    const int n0 = (int)(wg / gy) * 256;
    const int r0 = (int)(wg % gy) * 256;
    const int e  = blockIdx.z;

    int cnt = M_TOK, gbase = 0;
    if constexpr (MODE == 2 || MODE == 3) {
        cnt = counts[e];
        if (r0 >= cnt) return;
        gbase = basearr[e];
    }
    const int kbeg = (KSPLIT > 1) ? e * KCH : 0;
    const unsigned short* Bexp = Bbase + (size_t)e * (size_t)BSTR;

    // ---- staging source pointers: [half][i], pre-swizzled, fixed across K ----
    const unsigned short* aptr[2][2];
    const unsigned short* bptr[2][2];
#pragma unroll
    for (int h = 0; h < 2; ++h) {
#pragma unroll
        for (int i = 0; i < 2; ++i) {
            const int eo = (i * 512 + tid) * 8;        // elem offset in half [0,8192)
            const int prow = eo >> 6;                  // 0..127
            const int kch = ((eo >> 3) & 7) ^ (prow & 7);
            const int lrow = h * 128 + prow;
            int ar;
            if constexpr (MODE == 0 || MODE == 1) ar = r0 + lrow;
            else {
                int rr2 = r0 + lrow; if (rr2 > cnt - 1) rr2 = cnt - 1;
                ar = (MODE == 2) ? ltok[e * M_TOK + rr2] : (gbase + rr2);
            }
            aptr[h][i] = Abase + (size_t)ar * KDIM + kbeg + kch * 8;
            bptr[h][i] = Bexp + (size_t)(n0 + lrow) * KDIM + kbeg + kch * 8;
        }
    }

    f32x4 acc[8][4];
    const f32x4 z = {0.f, 0.f, 0.f, 0.f};
#pragma unroll
    for (int m = 0; m < 8; ++m)
#pragma unroll
        for (int n = 0; n < 4; ++n) acc[m][n] = z;

    auto STAGEA = [&](int h, int buf, int kt) {
#pragma unroll
        for (int i = 0; i < 2; ++i)
            gl16(aptr[h][i] + kt, &sA[buf * 16384 + h * 8192 + (i * 512 + tid) * 8]);
    };
    auto STAGEB = [&](int h, int buf, int kt) {
#pragma unroll
        for (int i = 0; i < 2; ++i)
            gl16(bptr[h][i] + kt, &sB[buf * 16384 + h * 8192 + (i * 512 + tid) * 8]);
    };

    // prologue: full tile 0 into buf 0, drain once
    STAGEA(0, 0, 0); STAGEB(0, 0, 0); STAGEB(1, 0, 0); STAGEA(1, 0, 0);
    asm volatile("s_waitcnt vmcnt(0)" ::: "memory");
    __builtin_amdgcn_s_barrier();

    short8 af[8], bfA[4], bfB[4];

#pragma unroll 1
    for (int t = 0; t < NT; ++t) {
        const int cur = t & 1, nxt = cur ^ 1;
        const int kt1 = (t + 1) * 64;
        const bool pf = (t + 1 < NT);
        const int cb = cur * 16384;

        // ---------- P1: (mh0, nh0) ----------
#pragma unroll
        for (int m = 0; m < 4; ++m) {
            const int row = wr * 64 + m * 16 + lr;
#pragma unroll
            for (int kk = 0; kk < 2; ++kk)
                af[m * 2 + kk] = *(const short8*)&sA[cb + (row << 6) + ((((kk << 2) + lk) ^ (row & 7)) << 3)];
        }
#pragma unroll
        for (int n = 0; n < 2; ++n) {
            const int row = wcol * 32 + n * 16 + lr;
#pragma unroll
            for (int kk = 0; kk < 2; ++kk)
                bfA[n * 2 + kk] = *(const short8*)&sB[cb + (row << 6) + ((((kk << 2) + lk) ^ (row & 7)) << 3)];
        }
        if (pf) STAGEA(0, nxt, kt1);
        __builtin_amdgcn_s_barrier();
        asm volatile("s_waitcnt lgkmcnt(0)" ::: "memory");
        __builtin_amdgcn_s_setprio(1);
#pragma unroll
        for (int kk = 0; kk < 2; ++kk)
#pragma unroll
            for (int n = 0; n < 2; ++n)
#pragma unroll
                for (int m = 0; m < 4; ++m)
                    acc[m][n] = __builtin_amdgcn_mfma_f32_16x16x32_bf16(af[m * 2 + kk], bfA[n * 2 + kk], acc[m][n], 0, 0, 0);
        __builtin_amdgcn_s_setprio(0);
        if (pf) asm volatile("s_waitcnt vmcnt(4)" ::: "memory");
        else    asm volatile("s_waitcnt vmcnt(2)" ::: "memory");   // drain B-hi(last)
        __builtin_amdgcn_s_barrier();

        // ---------- P2: (mh0, nh1) ----------
#pragma unroll
        for (int n = 0; n < 2; ++n) {
            const int row = 128 + wcol * 32 + n * 16 + lr;
#pragma unroll
            for (int kk = 0; kk < 2; ++kk)
                bfB[n * 2 + kk] = *(const short8*)&sB[cb + (row << 6) + ((((kk << 2) + lk) ^ (row & 7)) << 3)];
        }
        if (pf) STAGEB(0, nxt, kt1);
        __builtin_amdgcn_s_barrier();
        asm volatile("s_waitcnt lgkmcnt(0)" ::: "memory");
        __builtin_amdgcn_s_setprio(1);
#pragma unroll
        for (int kk = 0; kk < 2; ++kk)
#pragma unroll
            for (int n = 0; n < 2; ++n)
#pragma unroll
                for (int m = 0; m < 4; ++m)
                    acc[m][n + 2] = __builtin_amdgcn_mfma_f32_16x16x32_bf16(af[m * 2 + kk], bfB[n * 2 + kk], acc[m][n + 2], 0, 0, 0);
        __builtin_amdgcn_s_setprio(0);
        if (pf) asm volatile("s_waitcnt vmcnt(4)" ::: "memory");
        else    asm volatile("s_waitcnt vmcnt(0)" ::: "memory");   // drain A-hi(last)
        __builtin_amdgcn_s_barrier();

        // ---------- P3: (mh1, nh0) ----------
#pragma unroll
        for (int m = 0; m < 4; ++m) {
            const int row = 128 + wr * 64 + m * 16 + lr;
#pragma unroll
            for (int kk = 0; kk < 2; ++kk)
                af[m * 2 + kk] = *(const short8*)&sA[cb + (row << 6) + ((((kk << 2) + lk) ^ (row & 7)) << 3)];
        }
        if (pf) STAGEB(1, nxt, kt1);
        __builtin_amdgcn_s_barrier();
        asm volatile("s_waitcnt lgkmcnt(0)" ::: "memory");
        __builtin_amdgcn_s_setprio(1);
#pragma unroll
        for (int kk = 0; kk < 2; ++kk)
#pragma unroll
            for (int n = 0; n < 2; ++n)
#pragma unroll
                for (int m = 0; m < 4; ++m)
                    acc[m + 4][n] = __builtin_amdgcn_mfma_f32_16x16x32_bf16(af[m * 2 + kk], bfA[n * 2 + kk], acc[m + 4][n], 0, 0, 0);
        __builtin_amdgcn_s_setprio(0);
        __builtin_amdgcn_s_barrier();

        // ---------- P4: (mh1, nh1) ----------
        if (pf) STAGEA(1, nxt, kt1);
        __builtin_amdgcn_s_barrier();
        __builtin_amdgcn_s_setprio(1);
#pragma unroll
        for (int kk = 0; kk < 2; ++kk)
#pragma unroll
            for (int n = 0; n < 2; ++n)
#pragma unroll
                for (int m = 0; m < 4; ++m)
                    acc[m + 4][n + 2] = __builtin_amdgcn_mfma_f32_16x16x32_bf16(af[m * 2 + kk], bfB[n * 2 + kk], acc[m + 4][n + 2], 0, 0, 0);
        __builtin_amdgcn_s_setprio(0);
        asm volatile("s_waitcnt vmcnt(4)" ::: "memory");
        __builtin_amdgcn_s_barrier();
    }

    // ---- epilogue ----
    if constexpr (UP) {
        const int hc0 = (n0 >> 1) + wcol * 16 + lr;
        unsigned short* hb = (unsigned short*)outp;
#pragma unroll
        for (int m = 0; m < 8; ++m) {
            const int rb = (m < 4 ? wr * 64 + m * 16 : 128 + wr * 64 + (m - 4) * 16) + lk * 4;
#pragma unroll
            for (int j = 0; j < 4; ++j) {
                const int r = rb + j;
                bool ok; size_t orow;
                if constexpr (MODE == 0) { ok = true; orow = (size_t)(r0 + r) * OSTR; }
                else { ok = (r0 + r < cnt); orow = (size_t)(gbase + r0 + r) * OSTR; }
                if (ok) {
                    float g0 = acc[m][0][j], u0 = acc[m][1][j];
                    float g1 = acc[m][2][j], u1 = acc[m][3][j];
                    hb[orow + hc0]      = f2bf(g0 / (1.f + __expf(-g0)) * u0);
                    hb[orow + hc0 + 64] = f2bf(g1 / (1.f + __expf(-g1)) * u1);
                }
            }
        }
    } else {
        float* op = (float*)outp;
#pragma unroll
        for (int m = 0; m < 8; ++m) {
            const int rb = (m < 4 ? wr * 64 + m * 16 : 128 + wr * 64 + (m - 4) * 16) + lk * 4;
#pragma unroll
            for (int j = 0; j < 4; ++j) {
                const int r = rb + j;
                int tok; float scale; bool ok;
                if constexpr (MODE == 1) {
                    tok = r0 + r; scale = sg[tok]; ok = true;
                } else {
                    ok = (r0 + r < cnt);
                    int idx = ok ? (e * M_TOK + r0 + r) : (e * M_TOK);
                    tok = ltok[idx]; scale = lcoef[idx];
                }
                if (ok) {
                    size_t orow = (size_t)tok * H_DIM;
#pragma unroll
                    for (int n = 0; n < 4; ++n) {
                        const int col = n0 + (n < 2 ? wcol * 32 + n * 16 : 128 + wcol * 32 + (n - 2) * 16) + lr;
                        atomicAdd(op + orow + col, acc[m][n][j] * scale);
                    }
                }
            }
        }
    }
}

extern "C" void kernel_launch(void* const* d_in, const int* in_sizes, int n_in,
                              void* d_out, int out_size, void* d_ws, size_t ws_size,
                              hipStream_t stream) {
    const float* x    = (const float*)d_in[0];
    const float* gw   = (const float*)d_in[1];
    const float* sgw  = (const float*)d_in[2];
    const float* w13  = (const float*)d_in[3];
    const float* w2   = (const float*)d_in[4];
    const float* sguw = (const float*)d_in[5];
    const float* sdw  = (const float*)d_in[6];
    float* out = (float*)d_out;

    char* ws = (char*)d_ws;
    unsigned short* xb    = (unsigned short*)ws;                // 16,777,216 B
    unsigned short* hbuf  = (unsigned short*)(ws + 16777216);   // 46,137,344 B (hs then he)
    unsigned short* w13b  = (unsigned short*)(ws + 62914560);   // 184,549,376 B (permuted)
    unsigned short* w2b   = (unsigned short*)(ws + 247463936);  //  92,274,688 B
    unsigned short* sguwb = (unsigned short*)(ws + 339738624);  //  46,137,344 B (permuted)
    unsigned short* sdwb  = (unsigned short*)(ws + 385875968);  //  23,068,672 B
    size_t so = 408944640ULL;
    int*   ltok   = (int*)  (ws + so);
    float* lcoef  = (float*)(ws + so + 262144);
    int*   counts = (int*)  (ws + so + 524288);
    int*   basep  = (int*)  (ws + so + 524288 + 256);
    float* sg     = (float*)(ws + so + 524288 + 512);

    hipMemsetAsync(counts, 0, 64, stream);
    hipMemsetAsync(out, 0, (size_t)out_size * sizeof(float), stream);
    k_router<<<M_TOK / 4, 256, 0, stream>>>(x, gw, sgw, counts, ltok, lcoef, sg);
    k_prefix<<<1, 64, 0, stream>>>(counts, basep);
    k_cvtw<<<4096, 256, 0, stream>>>(x, xb, (size_t)M_TOK * H_DIM / 8);
    k_cvtp<2 * IS_DIM, IS_DIM><<<8192, 256, 0, stream>>>(sguw, sguwb, (size_t)2 * IS_DIM * H_DIM / 8);
    k_cvtw<<<8192, 256, 0, stream>>>(sdw,  sdwb,  (size_t)H_DIM * IS_DIM / 8);
    k_cvtp<2 * I_DIM, I_DIM><<<8192, 256, 0, stream>>>(w13, w13b, (size_t)E_NUM * 2 * I_DIM * H_DIM / 8);
    k_cvtw<<<8192, 256, 0, stream>>>(w2,   w2b,   (size_t)E_NUM * H_DIM * I_DIM / 8);

    static const int DYN = 131072;
    (void)hipFuncSetAttribute(reinterpret_cast<const void*>(&k_gemm<0, 2048, 0LL, 1>),
                              hipFuncAttributeMaxDynamicSharedMemorySize, DYN);
    (void)hipFuncSetAttribute(reinterpret_cast<const void*>(&k_gemm<1, 5632, 0LL, 2>),
                              hipFuncAttributeMaxDynamicSharedMemorySize, DYN);
    (void)hipFuncSetAttribute(reinterpret_cast<const void*>(&k_gemm<2, 2048, 5767168LL, 1>),
                              hipFuncAttributeMaxDynamicSharedMemorySize, DYN);
    (void)hipFuncSetAttribute(reinterpret_cast<const void*>(&k_gemm<3, 1408, 2883584LL, 1>),
                              hipFuncAttributeMaxDynamicSharedMemorySize, DYN);

    // shared up: xb[4096,2048] x sguwb^T -> silu-mul pairs -> hs bf16 [4096,5632]
    k_gemm<0, 2048, 0LL, 1>
        <<<dim3(2 * IS_DIM / 256, M_TOK / 256, 1), 512, DYN, stream>>>(
            xb, sguwb, hbuf, ltok, lcoef, counts, basep, sg);
    // shared down (split-K=2): hs x sdwb^T * sg -> atomicAdd out
    k_gemm<1, 5632, 0LL, 2>
        <<<dim3(H_DIM / 256, M_TOK / 256, 2), 512, DYN, stream>>>(
            hbuf, sdwb, out, ltok, lcoef, counts, basep, sg);
    // expert up (gathered): xb x w13b_e^T -> silu-mul -> he bf16 [16384,1408]
    k_gemm<2, 2048, 5767168LL, 1>
        <<<dim3(2 * I_DIM / 256, M_TOK / 256, E_NUM), 512, DYN, stream>>>(
            xb, w13b, hbuf, ltok, lcoef, counts, basep, sg);
    // expert down: he x w2b_e^T * coef -> atomicAdd out
    k_gemm<3, 1408, 2883584LL, 1>
        <<<dim3(H_DIM / 256, M_TOK / 256, E_NUM), 512, DYN, stream>>>(
            hbuf, w2b, out, ltok, lcoef, counts, basep, sg);
}

// Round 9
// 1215.022 us; speedup vs baseline: 1.0514x; 1.0315x over previous
//
#include <hip/hip_runtime.h>
#include <hip/hip_bf16.h>

// ---- problem constants ----
#define E_NUM 16
#define TOPK 4
#define H_DIM 2048
#define I_DIM 1408
#define IS_DIM 5632
#define M_TOK 4096

typedef __attribute__((ext_vector_type(8))) short short8;
typedef __attribute__((ext_vector_type(4))) float f32x4;

static __device__ __forceinline__ unsigned short f2bf(float f) {
    unsigned int u = __float_as_uint(f);
    unsigned int r = (u + 0x7FFFu + ((u >> 16) & 1u)) >> 16;
    return (unsigned short)r;
}

static __device__ __forceinline__ void gl16(const unsigned short* g, unsigned short* l) {
    __builtin_amdgcn_global_load_lds(
        (const __attribute__((address_space(1))) unsigned int*)g,
        (__attribute__((address_space(3))) unsigned int*)l, 16, 0, 0);
}

// ---------------- router: fp32 logits, softmax, top-4, shared gate ----------------
__global__ __launch_bounds__(256) void k_router(
    const float* __restrict__ x, const float* __restrict__ gw,
    const float* __restrict__ sgw, int* __restrict__ counts,
    int* __restrict__ ltok, float* __restrict__ lcoef, float* __restrict__ sg)
{
    const int wid = threadIdx.x >> 6, lane = threadIdx.x & 63;
    const int t = blockIdx.x * 4 + wid;
    const float* xr = x + (size_t)t * H_DIM;
    float xv[32];
#pragma unroll
    for (int i = 0; i < 32; ++i) xv[i] = xr[i * 64 + lane];

    float lg[E_NUM];
    for (int e = 0; e < E_NUM; ++e) {
        const float* g = gw + (size_t)e * H_DIM;
        float s = 0.f;
#pragma unroll
        for (int i = 0; i < 32; ++i) s += xv[i] * g[i * 64 + lane];
#pragma unroll
        for (int off = 32; off; off >>= 1) s += __shfl_xor(s, off);
        lg[e] = s;
    }
    {
        float s = 0.f;
#pragma unroll
        for (int i = 0; i < 32; ++i) s += xv[i] * sgw[i * 64 + lane];
#pragma unroll
        for (int off = 32; off; off >>= 1) s += __shfl_xor(s, off);
        if (lane == 0) sg[t] = 1.f / (1.f + __expf(-s));
    }
    float mx = lg[0];
#pragma unroll
    for (int e = 1; e < E_NUM; ++e) mx = fmaxf(mx, lg[e]);
    float sum = 0.f, w[E_NUM];
#pragma unroll
    for (int e = 0; e < E_NUM; ++e) { w[e] = __expf(lg[e] - mx); sum += w[e]; }
    float inv = 1.f / sum;
#pragma unroll
    for (int e = 0; e < E_NUM; ++e) w[e] *= inv;

    if (lane == 0) {
        for (int j = 0; j < TOPK; ++j) {
            float best = -1.f; int bi = 0;
            for (int e = 0; e < E_NUM; ++e) if (w[e] > best) { best = w[e]; bi = e; }
            int pos = atomicAdd(&counts[bi], 1);
            ltok[bi * M_TOK + pos]  = t;
            lcoef[bi * M_TOK + pos] = best;
            w[bi] = -2.f;
        }
    }
}

__global__ void k_prefix(const int* __restrict__ counts, int* __restrict__ base) {
    if (threadIdx.x == 0) {
        int a = 0;
        for (int e = 0; e < E_NUM; ++e) { base[e] = a; a += counts[e]; }
        base[E_NUM] = a;
    }
}

// ---------------- fp32 -> bf16 conversion (grid-stride) ----------------
__global__ __launch_bounds__(256) void k_cvtw(const float* __restrict__ src,
                                              unsigned short* __restrict__ dst, size_t n8)
{
    size_t stride = (size_t)gridDim.x * 256;
    for (size_t t = (size_t)blockIdx.x * 256 + threadIdx.x; t < n8; t += stride) {
        size_t i = t * 8;
        float4 a = *(const float4*)(src + i);
        float4 b = *(const float4*)(src + i + 4);
        union { unsigned short u[8]; short8 v; } o;
        o.u[0] = f2bf(a.x); o.u[1] = f2bf(a.y); o.u[2] = f2bf(a.z); o.u[3] = f2bf(a.w);
        o.u[4] = f2bf(b.x); o.u[5] = f2bf(b.y); o.u[6] = f2bf(b.z); o.u[7] = f2bf(b.w);
        *(short8*)(dst + i) = o.v;
    }
}

// fp32 -> bf16 with gate/up 16-row-chunk interleave within TWOI-row groups.
template<int TWOI, int NOFF>
__global__ __launch_bounds__(256) void k_cvtp(const float* __restrict__ src,
                                              unsigned short* __restrict__ dst, size_t n8)
{
    size_t stride = (size_t)gridDim.x * 256;
    for (size_t t = (size_t)blockIdx.x * 256 + threadIdx.x; t < n8; t += stride) {
        size_t i = t * 8;
        unsigned drow = (unsigned)(i >> 11);
        unsigned col  = (unsigned)(i & 2047u);
        unsigned grp = drow / (unsigned)TWOI;
        unsigned rr  = drow - grp * (unsigned)TWOI;
        unsigned q = rr >> 4, rm = rr & 15u;
        unsigned srow = ((q >> 1) << 4) + rm + ((q & 1u) ? (unsigned)NOFF : 0u);
        const float* s = src + (((size_t)grp * TWOI + srow) << 11) + col;
        float4 a = *(const float4*)s;
        float4 b = *(const float4*)(s + 4);
        union { unsigned short u[8]; short8 v; } o;
        o.u[0] = f2bf(a.x); o.u[1] = f2bf(a.y); o.u[2] = f2bf(a.z); o.u[3] = f2bf(a.w);
        o.u[4] = f2bf(b.x); o.u[5] = f2bf(b.y); o.u[6] = f2bf(b.z); o.u[7] = f2bf(b.w);
        *(short8*)(dst + i) = o.v;
    }
}

// ---------------- 256x256 2-superphase pipelined bf16 MFMA GEMM ----------------
// Per K-tile: SP1 = {read Alo,Blo; issue stage Alo,Blo(t+1); 16 MFMA;
// vmcnt(4); barrier}  SP2 = {read Bhi; issue stage Bhi,Ahi(t+1); 16 MFMA;
// read Ahi; 32 MFMA; vmcnt(4); barrier}. Only 2 [vmcnt;barrier] pairs per
// K-tile; issue->deadline distance ~1 K-tile. Last tile: SP1 vmcnt(0).
template<int MODE, int KDIM, long long BSTR, int KSPLIT>
__global__ __launch_bounds__(512, 2) void k_gemm(
    const unsigned short* __restrict__ Abase,
    const unsigned short* __restrict__ Bbase,
    void* __restrict__ outp,
    const int* __restrict__ ltok, const float* __restrict__ lcoef,
    const int* __restrict__ counts, const int* __restrict__ basearr,
    const float* __restrict__ sg)
{
    constexpr bool UP = (MODE == 0 || MODE == 2);
    constexpr int OSTR = (MODE == 0) ? IS_DIM : I_DIM;   // h row stride (UP only)
    constexpr int KCH = KDIM / KSPLIT;
    constexpr int NT = KCH / 64;

    extern __shared__ unsigned short smem[];
    unsigned short* sA = smem;            // [2 buf][256 rows][64]
    unsigned short* sB = smem + 32768;    // [2 buf][256 rows][64]

    const int tid = threadIdx.x;
    const int lane = tid & 63, wid = tid >> 6;
    const int wr = wid >> 2, wcol = wid & 3;
    const int lr = lane & 15, lk = lane >> 4;

    // ---- bijective XCD-chunk swizzle over (x,y), y-major within chunk ----
    const unsigned gx = gridDim.x, gy = gridDim.y;
    const unsigned nwg = gx * gy;
    const unsigned orig = blockIdx.y * gx + blockIdx.x;
    const unsigned q8 = nwg >> 3, r8 = nwg & 7;
    const unsigned xcd = orig & 7, off8 = orig >> 3;
    const unsigned wg = ((xcd < r8) ? xcd * (q8 + 1) : r8 * (q8 + 1) + (xcd - r8) * q8) + off8;
    const int n0 = (int)(wg / gy) * 256;
    const int r0 = (int)(wg % gy) * 256;
    const int e  = blockIdx.z;

    int cnt = M_TOK, gbase = 0;
    if constexpr (MODE == 2 || MODE == 3) {
        cnt = counts[e];
        if (r0 >= cnt) return;
        gbase = basearr[e];
    }
    const int kbeg = (KSPLIT > 1) ? e * KCH : 0;
    const unsigned short* Bexp = Bbase + (size_t)e * (size_t)BSTR;

    // ---- staging source pointers: [half][i], pre-swizzled, fixed across K ----
    const unsigned short* aptr[2][2];
    const unsigned short* bptr[2][2];
#pragma unroll
    for (int h = 0; h < 2; ++h) {
#pragma unroll
        for (int i = 0; i < 2; ++i) {
            const int eo = (i * 512 + tid) * 8;        // elem offset in half [0,8192)
            const int prow = eo >> 6;                  // 0..127
            const int kch = ((eo >> 3) & 7) ^ (prow & 7);
            const int lrow = h * 128 + prow;
            int ar;
            if constexpr (MODE == 0 || MODE == 1) ar = r0 + lrow;
            else {
                int rr2 = r0 + lrow; if (rr2 > cnt - 1) rr2 = cnt - 1;
                ar = (MODE == 2) ? ltok[e * M_TOK + rr2] : (gbase + rr2);
            }
            aptr[h][i] = Abase + (size_t)ar * KDIM + kbeg + kch * 8;
            bptr[h][i] = Bexp + (size_t)(n0 + lrow) * KDIM + kbeg + kch * 8;
        }
    }

    f32x4 acc[8][4];
    const f32x4 z = {0.f, 0.f, 0.f, 0.f};
#pragma unroll
    for (int m = 0; m < 8; ++m)
#pragma unroll
        for (int n = 0; n < 4; ++n) acc[m][n] = z;

    auto STAGEA = [&](int h, int buf, int kt) {
#pragma unroll
        for (int i = 0; i < 2; ++i)
            gl16(aptr[h][i] + kt, &sA[buf * 16384 + h * 8192 + (i * 512 + tid) * 8]);
    };
    auto STAGEB = [&](int h, int buf, int kt) {
#pragma unroll
        for (int i = 0; i < 2; ++i)
            gl16(bptr[h][i] + kt, &sB[buf * 16384 + h * 8192 + (i * 512 + tid) * 8]);
    };

    // prologue: tile 0 in issue order [Alo,Blo,Bhi,Ahi]; wait only Alo,Blo
    STAGEA(0, 0, 0); STAGEB(0, 0, 0); STAGEB(1, 0, 0); STAGEA(1, 0, 0);
    asm volatile("s_waitcnt vmcnt(4)" ::: "memory");
    __builtin_amdgcn_s_barrier();

    short8 af[8], bfA[4], bfB[4];

#pragma unroll 1
    for (int t = 0; t < NT; ++t) {
        const int cur = t & 1, nxt = cur ^ 1;
        const int kt1 = (t + 1) * 64;
        const bool pf = (t + 1 < NT);
        const int cb = cur * 16384;

        // ========== SP1: (mh0, nh0) ==========
#pragma unroll
        for (int m = 0; m < 4; ++m) {
            const int row = wr * 64 + m * 16 + lr;
#pragma unroll
            for (int kk = 0; kk < 2; ++kk)
                af[m * 2 + kk] = *(const short8*)&sA[cb + (row << 6) + ((((kk << 2) + lk) ^ (row & 7)) << 3)];
        }
#pragma unroll
        for (int n = 0; n < 2; ++n) {
            const int row = wcol * 32 + n * 16 + lr;
#pragma unroll
            for (int kk = 0; kk < 2; ++kk)
                bfA[n * 2 + kk] = *(const short8*)&sB[cb + (row << 6) + ((((kk << 2) + lk) ^ (row & 7)) << 3)];
        }
        if (pf) { STAGEA(0, nxt, kt1); STAGEB(0, nxt, kt1); }
        __builtin_amdgcn_s_setprio(1);
#pragma unroll
        for (int kk = 0; kk < 2; ++kk)
#pragma unroll
            for (int n = 0; n < 2; ++n)
#pragma unroll
                for (int m = 0; m < 4; ++m)
                    acc[m][n] = __builtin_amdgcn_mfma_f32_16x16x32_bf16(af[m * 2 + kk], bfA[n * 2 + kk], acc[m][n], 0, 0, 0);
        __builtin_amdgcn_s_setprio(0);
        if (pf) asm volatile("s_waitcnt vmcnt(4)" ::: "memory");   // Bhi(t),Ahi(t) landed
        else    asm volatile("s_waitcnt vmcnt(0)" ::: "memory");   // last tile: drain
        __builtin_amdgcn_s_barrier();

        // ========== SP2: (mh0,nh1) + (mh1,nh0) + (mh1,nh1) ==========
#pragma unroll
        for (int n = 0; n < 2; ++n) {
            const int row = 128 + wcol * 32 + n * 16 + lr;
#pragma unroll
            for (int kk = 0; kk < 2; ++kk)
                bfB[n * 2 + kk] = *(const short8*)&sB[cb + (row << 6) + ((((kk << 2) + lk) ^ (row & 7)) << 3)];
        }
        if (pf) { STAGEB(1, nxt, kt1); STAGEA(1, nxt, kt1); }
        __builtin_amdgcn_s_setprio(1);
#pragma unroll
        for (int kk = 0; kk < 2; ++kk)
#pragma unroll
            for (int n = 0; n < 2; ++n)
#pragma unroll
                for (int m = 0; m < 4; ++m)
                    acc[m][n + 2] = __builtin_amdgcn_mfma_f32_16x16x32_bf16(af[m * 2 + kk], bfB[n * 2 + kk], acc[m][n + 2], 0, 0, 0);
        __builtin_amdgcn_s_setprio(0);

#pragma unroll
        for (int m = 0; m < 4; ++m) {
            const int row = 128 + wr * 64 + m * 16 + lr;
#pragma unroll
            for (int kk = 0; kk < 2; ++kk)
                af[m * 2 + kk] = *(const short8*)&sA[cb + (row << 6) + ((((kk << 2) + lk) ^ (row & 7)) << 3)];
        }
        __builtin_amdgcn_s_setprio(1);
#pragma unroll
        for (int kk = 0; kk < 2; ++kk)
#pragma unroll
            for (int n = 0; n < 2; ++n)
#pragma unroll
                for (int m = 0; m < 4; ++m)
                    acc[m + 4][n] = __builtin_amdgcn_mfma_f32_16x16x32_bf16(af[m * 2 + kk], bfA[n * 2 + kk], acc[m + 4][n], 0, 0, 0);
#pragma unroll
        for (int kk = 0; kk < 2; ++kk)
#pragma unroll
            for (int n = 0; n < 2; ++n)
#pragma unroll
                for (int m = 0; m < 4; ++m)
                    acc[m + 4][n + 2] = __builtin_amdgcn_mfma_f32_16x16x32_bf16(af[m * 2 + kk], bfB[n * 2 + kk], acc[m + 4][n + 2], 0, 0, 0);
        __builtin_amdgcn_s_setprio(0);
        asm volatile("s_waitcnt vmcnt(4)" ::: "memory");   // Alo(t+1),Blo(t+1) landed
        __builtin_amdgcn_s_barrier();
    }

    // ---- epilogue ----
    if constexpr (UP) {
        const int hc0 = (n0 >> 1) + wcol * 16 + lr;
        unsigned short* hb = (unsigned short*)outp;
#pragma unroll
        for (int m = 0; m < 8; ++m) {
            const int rb = (m < 4 ? wr * 64 + m * 16 : 128 + wr * 64 + (m - 4) * 16) + lk * 4;
#pragma unroll
            for (int j = 0; j < 4; ++j) {
                const int r = rb + j;
                bool ok; size_t orow;
                if constexpr (MODE == 0) { ok = true; orow = (size_t)(r0 + r) * OSTR; }
                else { ok = (r0 + r < cnt); orow = (size_t)(gbase + r0 + r) * OSTR; }
                if (ok) {
                    float g0 = acc[m][0][j], u0 = acc[m][1][j];
                    float g1 = acc[m][2][j], u1 = acc[m][3][j];
                    hb[orow + hc0]      = f2bf(g0 / (1.f + __expf(-g0)) * u0);
                    hb[orow + hc0 + 64] = f2bf(g1 / (1.f + __expf(-g1)) * u1);
                }
            }
        }
    } else {
        float* op = (float*)outp;
#pragma unroll
        for (int m = 0; m < 8; ++m) {
            const int rb = (m < 4 ? wr * 64 + m * 16 : 128 + wr * 64 + (m - 4) * 16) + lk * 4;
#pragma unroll
            for (int j = 0; j < 4; ++j) {
                const int r = rb + j;
                int tok; float scale; bool ok;
                if constexpr (MODE == 1) {
                    tok = r0 + r; scale = sg[tok]; ok = true;
                } else {
                    ok = (r0 + r < cnt);
                    int idx = ok ? (e * M_TOK + r0 + r) : (e * M_TOK);
                    tok = ltok[idx]; scale = lcoef[idx];
                }
                if (ok) {
                    size_t orow = (size_t)tok * H_DIM;
#pragma unroll
                    for (int n = 0; n < 4; ++n) {
                        const int col = n0 + (n < 2 ? wcol * 32 + n * 16 : 128 + wcol * 32 + (n - 2) * 16) + lr;
                        atomicAdd(op + orow + col, acc[m][n][j] * scale);
                    }
                }
            }
        }
    }
}

extern "C" void kernel_launch(void* const* d_in, const int* in_sizes, int n_in,
                              void* d_out, int out_size, void* d_ws, size_t ws_size,
                              hipStream_t stream) {
    const float* x    = (const float*)d_in[0];
    const float* gw   = (const float*)d_in[1];
    const float* sgw  = (const float*)d_in[2];
    const float* w13  = (const float*)d_in[3];
    const float* w2   = (const float*)d_in[4];
    const float* sguw = (const float*)d_in[5];
    const float* sdw  = (const float*)d_in[6];
    float* out = (float*)d_out;

    char* ws = (char*)d_ws;
    unsigned short* xb    = (unsigned short*)ws;                // 16,777,216 B
    unsigned short* hbuf  = (unsigned short*)(ws + 16777216);   // 46,137,344 B (hs then he)
    unsigned short* w13b  = (unsigned short*)(ws + 62914560);   // 184,549,376 B (permuted)
    unsigned short* w2b   = (unsigned short*)(ws + 247463936);  //  92,274,688 B
    unsigned short* sguwb = (unsigned short*)(ws + 339738624);  //  46,137,344 B (permuted)
    unsigned short* sdwb  = (unsigned short*)(ws + 385875968);  //  23,068,672 B
    size_t so = 408944640ULL;
    int*   ltok   = (int*)  (ws + so);
    float* lcoef  = (float*)(ws + so + 262144);
    int*   counts = (int*)  (ws + so + 524288);
    int*   basep  = (int*)  (ws + so + 524288 + 256);
    float* sg     = (float*)(ws + so + 524288 + 512);

    hipMemsetAsync(counts, 0, 64, stream);
    hipMemsetAsync(out, 0, (size_t)out_size * sizeof(float), stream);
    k_router<<<M_TOK / 4, 256, 0, stream>>>(x, gw, sgw, counts, ltok, lcoef, sg);
    k_prefix<<<1, 64, 0, stream>>>(counts, basep);
    k_cvtw<<<4096, 256, 0, stream>>>(x, xb, (size_t)M_TOK * H_DIM / 8);
    k_cvtp<2 * IS_DIM, IS_DIM><<<8192, 256, 0, stream>>>(sguw, sguwb, (size_t)2 * IS_DIM * H_DIM / 8);
    k_cvtw<<<8192, 256, 0, stream>>>(sdw,  sdwb,  (size_t)H_DIM * IS_DIM / 8);
    k_cvtp<2 * I_DIM, I_DIM><<<8192, 256, 0, stream>>>(w13, w13b, (size_t)E_NUM * 2 * I_DIM * H_DIM / 8);
    k_cvtw<<<8192, 256, 0, stream>>>(w2,   w2b,   (size_t)E_NUM * H_DIM * I_DIM / 8);

    static const int DYN = 131072;
    (void)hipFuncSetAttribute(reinterpret_cast<const void*>(&k_gemm<0, 2048, 0LL, 1>),
                              hipFuncAttributeMaxDynamicSharedMemorySize, DYN);
    (void)hipFuncSetAttribute(reinterpret_cast<const void*>(&k_gemm<1, 5632, 0LL, 2>),
                              hipFuncAttributeMaxDynamicSharedMemorySize, DYN);
    (void)hipFuncSetAttribute(reinterpret_cast<const void*>(&k_gemm<2, 2048, 5767168LL, 1>),
                              hipFuncAttributeMaxDynamicSharedMemorySize, DYN);
    (void)hipFuncSetAttribute(reinterpret_cast<const void*>(&k_gemm<3, 1408, 2883584LL, 1>),
                              hipFuncAttributeMaxDynamicSharedMemorySize, DYN);

    // shared up: xb[4096,2048] x sguwb^T -> silu-mul pairs -> hs bf16 [4096,5632]
    k_gemm<0, 2048, 0LL, 1>
        <<<dim3(2 * IS_DIM / 256, M_TOK / 256, 1), 512, DYN, stream>>>(
            xb, sguwb, hbuf, ltok, lcoef, counts, basep, sg);
    // shared down (split-K=2): hs x sdwb^T * sg -> atomicAdd out
    k_gemm<1, 5632, 0LL, 2>
        <<<dim3(H_DIM / 256, M_TOK / 256, 2), 512, DYN, stream>>>(
            hbuf, sdwb, out, ltok, lcoef, counts, basep, sg);
    // expert up (gathered): xb x w13b_e^T -> silu-mul -> he bf16 [16384,1408]
    k_gemm<2, 2048, 5767168LL, 1>
        <<<dim3(2 * I_DIM / 256, M_TOK / 256, E_NUM), 512, DYN, stream>>>(
            xb, w13b, hbuf, ltok, lcoef, counts, basep, sg);
    // expert down: he x w2b_e^T * coef -> atomicAdd out
    k_gemm<3, 1408, 2883584LL, 1>
        <<<dim3(H_DIM / 256, M_TOK / 256, E_NUM), 512, DYN, stream>>>(
            hbuf, w2b, out, ltok, lcoef, counts, basep, sg);
}

// Round 10
// 1197.320 us; speedup vs baseline: 1.0670x; 1.0148x over previous
//
#include <hip/hip_runtime.h>
#include <hip/hip_bf16.h>

// ---- problem constants ----
#define E_NUM 16
#define TOPK 4
#define H_DIM 2048
#define I_DIM 1408
#define IS_DIM 5632
#define M_TOK 4096

typedef __attribute__((ext_vector_type(8))) short short8;
typedef __attribute__((ext_vector_type(4))) float f32x4;

static __device__ __forceinline__ unsigned short f2bf(float f) {
    unsigned int u = __float_as_uint(f);
    unsigned int r = (u + 0x7FFFu + ((u >> 16) & 1u)) >> 16;
    return (unsigned short)r;
}

static __device__ __forceinline__ void gl16(const unsigned short* g, unsigned short* l) {
    __builtin_amdgcn_global_load_lds(
        (const __attribute__((address_space(1))) unsigned int*)g,
        (__attribute__((address_space(3))) unsigned int*)l, 16, 0, 0);
}

// ---------------- router: fp32 logits, softmax, top-4, shared gate ----------------
__global__ __launch_bounds__(256) void k_router(
    const float* __restrict__ x, const float* __restrict__ gw,
    const float* __restrict__ sgw, int* __restrict__ counts,
    int* __restrict__ ltok, float* __restrict__ lcoef, float* __restrict__ sg)
{
    const int wid = threadIdx.x >> 6, lane = threadIdx.x & 63;
    const int t = blockIdx.x * 4 + wid;
    const float* xr = x + (size_t)t * H_DIM;
    float xv[32];
#pragma unroll
    for (int i = 0; i < 32; ++i) xv[i] = xr[i * 64 + lane];

    float lg[E_NUM];
    for (int e = 0; e < E_NUM; ++e) {
        const float* g = gw + (size_t)e * H_DIM;
        float s = 0.f;
#pragma unroll
        for (int i = 0; i < 32; ++i) s += xv[i] * g[i * 64 + lane];
#pragma unroll
        for (int off = 32; off; off >>= 1) s += __shfl_xor(s, off);
        lg[e] = s;
    }
    {
        float s = 0.f;
#pragma unroll
        for (int i = 0; i < 32; ++i) s += xv[i] * sgw[i * 64 + lane];
#pragma unroll
        for (int off = 32; off; off >>= 1) s += __shfl_xor(s, off);
        if (lane == 0) sg[t] = 1.f / (1.f + __expf(-s));
    }
    float mx = lg[0];
#pragma unroll
    for (int e = 1; e < E_NUM; ++e) mx = fmaxf(mx, lg[e]);
    float sum = 0.f, w[E_NUM];
#pragma unroll
    for (int e = 0; e < E_NUM; ++e) { w[e] = __expf(lg[e] - mx); sum += w[e]; }
    float inv = 1.f / sum;
#pragma unroll
    for (int e = 0; e < E_NUM; ++e) w[e] *= inv;

    if (lane == 0) {
        for (int j = 0; j < TOPK; ++j) {
            float best = -1.f; int bi = 0;
            for (int e = 0; e < E_NUM; ++e) if (w[e] > best) { best = w[e]; bi = e; }
            int pos = atomicAdd(&counts[bi], 1);
            ltok[bi * M_TOK + pos]  = t;
            lcoef[bi * M_TOK + pos] = best;
            w[bi] = -2.f;
        }
    }
}

__global__ void k_prefix(const int* __restrict__ counts, int* __restrict__ base) {
    if (threadIdx.x == 0) {
        int a = 0;
        for (int e = 0; e < E_NUM; ++e) { base[e] = a; a += counts[e]; }
        base[E_NUM] = a;
    }
}

// ---------------- fp32 -> bf16 conversion (grid-stride) ----------------
__global__ __launch_bounds__(256) void k_cvtw(const float* __restrict__ src,
                                              unsigned short* __restrict__ dst, size_t n8)
{
    size_t stride = (size_t)gridDim.x * 256;
    for (size_t t = (size_t)blockIdx.x * 256 + threadIdx.x; t < n8; t += stride) {
        size_t i = t * 8;
        float4 a = *(const float4*)(src + i);
        float4 b = *(const float4*)(src + i + 4);
        union { unsigned short u[8]; short8 v; } o;
        o.u[0] = f2bf(a.x); o.u[1] = f2bf(a.y); o.u[2] = f2bf(a.z); o.u[3] = f2bf(a.w);
        o.u[4] = f2bf(b.x); o.u[5] = f2bf(b.y); o.u[6] = f2bf(b.z); o.u[7] = f2bf(b.w);
        *(short8*)(dst + i) = o.v;
    }
}

// fp32 -> bf16 with gate/up 16-row-chunk interleave within TWOI-row groups.
template<int TWOI, int NOFF>
__global__ __launch_bounds__(256) void k_cvtp(const float* __restrict__ src,
                                              unsigned short* __restrict__ dst, size_t n8)
{
    size_t stride = (size_t)gridDim.x * 256;
    for (size_t t = (size_t)blockIdx.x * 256 + threadIdx.x; t < n8; t += stride) {
        size_t i = t * 8;
        unsigned drow = (unsigned)(i >> 11);
        unsigned col  = (unsigned)(i & 2047u);
        unsigned grp = drow / (unsigned)TWOI;
        unsigned rr  = drow - grp * (unsigned)TWOI;
        unsigned q = rr >> 4, rm = rr & 15u;
        unsigned srow = ((q >> 1) << 4) + rm + ((q & 1u) ? (unsigned)NOFF : 0u);
        const float* s = src + (((size_t)grp * TWOI + srow) << 11) + col;
        float4 a = *(const float4*)s;
        float4 b = *(const float4*)(s + 4);
        union { unsigned short u[8]; short8 v; } o;
        o.u[0] = f2bf(a.x); o.u[1] = f2bf(a.y); o.u[2] = f2bf(a.z); o.u[3] = f2bf(a.w);
        o.u[4] = f2bf(b.x); o.u[5] = f2bf(b.y); o.u[6] = f2bf(b.z); o.u[7] = f2bf(b.w);
        *(short8*)(dst + i) = o.v;
    }
}

// ---------------- 256x128 3-deep-pipelined bf16 MFMA GEMM ----------------
// BM=256, BN=128, BK=64. 512 threads = 8 waves (4M x 2N), per-wave 64x64.
// THREE LDS buffers (A 3x32KB + B 3x16KB = 144 KiB): tile t reads buf[t%3],
// stages tile t+2 into buf[(t+2)%3]; ONE barrier + ONE counted vmcnt per
// K-tile (6 loads/thread/tile in flight 2 tiles deep; wait leaves exactly
// this tile's 6). Last tiles wait vmcnt(0) (= nothing issued this tile).
// Requires NT >= 2.
template<int MODE, int KDIM, long long BSTR, int KSPLIT>
__global__ __launch_bounds__(512, 2) void k_gemm(
    const unsigned short* __restrict__ Abase,
    const unsigned short* __restrict__ Bbase,
    void* __restrict__ outp,
    const int* __restrict__ ltok, const float* __restrict__ lcoef,
    const int* __restrict__ counts, const int* __restrict__ basearr,
    const float* __restrict__ sg)
{
    constexpr bool UP = (MODE == 0 || MODE == 2);
    constexpr int OSTR = (MODE == 0) ? IS_DIM : I_DIM;   // h row stride (UP only)
    constexpr int KCH = KDIM / KSPLIT;
    constexpr int NT = KCH / 64;

    extern __shared__ unsigned short smem[];
    unsigned short* sA = smem;            // [3 buf][256 rows][64]
    unsigned short* sB = smem + 49152;    // [3 buf][128 rows][64]

    const int tid = threadIdx.x;
    const int lane = tid & 63, wid = tid >> 6;
    const int wr = wid >> 1, wc = wid & 1;       // 4M x 2N wave grid
    const int lr = lane & 15, lk = lane >> 4;

    // ---- bijective XCD-chunk swizzle over (x,y), y-major within chunk ----
    const unsigned gx = gridDim.x, gy = gridDim.y;
    const unsigned nwg = gx * gy;
    const unsigned orig = blockIdx.y * gx + blockIdx.x;
    const unsigned q8 = nwg >> 3, r8 = nwg & 7;
    const unsigned xcd = orig & 7, off8 = orig >> 3;
    const unsigned wg = ((xcd < r8) ? xcd * (q8 + 1) : r8 * (q8 + 1) + (xcd - r8) * q8) + off8;
    const int n0 = (int)(wg / gy) * 128;
    const int r0 = (int)(wg % gy) * 256;
    const int e  = blockIdx.z;

    int cnt = M_TOK, gbase = 0;
    if constexpr (MODE == 2 || MODE == 3) {
        cnt = counts[e];
        if (r0 >= cnt) return;
        gbase = basearr[e];
    }
    const int kbeg = (KSPLIT > 1) ? e * KCH : 0;
    const unsigned short* Bexp = Bbase + (size_t)e * (size_t)BSTR;

    // ---- staging source pointers (pre-swizzled, fixed across K) ----
    const unsigned short* aptr[2][2];
#pragma unroll
    for (int h = 0; h < 2; ++h) {
#pragma unroll
        for (int i = 0; i < 2; ++i) {
            const int eo = (i * 512 + tid) * 8;        // elem offset in 128-row half
            const int prow = eo >> 6;                  // 0..127
            const int kch = ((eo >> 3) & 7) ^ (prow & 7);
            const int lrow = h * 128 + prow;
            int ar;
            if constexpr (MODE == 0 || MODE == 1) ar = r0 + lrow;
            else {
                int rr2 = r0 + lrow; if (rr2 > cnt - 1) rr2 = cnt - 1;
                ar = (MODE == 2) ? ltok[e * M_TOK + rr2] : (gbase + rr2);
            }
            aptr[h][i] = Abase + (size_t)ar * KDIM + kbeg + kch * 8;
        }
    }
    const unsigned short* bptr[2];
#pragma unroll
    for (int i = 0; i < 2; ++i) {
        const int eo = (i * 512 + tid) * 8;
        const int prow = eo >> 6;                      // 0..127
        const int kch = ((eo >> 3) & 7) ^ (prow & 7);
        bptr[i] = Bexp + (size_t)(n0 + prow) * KDIM + kbeg + kch * 8;
    }

    f32x4 acc[4][4];
    const f32x4 z = {0.f, 0.f, 0.f, 0.f};
#pragma unroll
    for (int m = 0; m < 4; ++m)
#pragma unroll
        for (int n = 0; n < 4; ++n) acc[m][n] = z;

    auto STAGE = [&](int buf, int kt) {
#pragma unroll
        for (int i = 0; i < 2; ++i)
            gl16(aptr[0][i] + kt, &sA[buf * 16384 + (i * 512 + tid) * 8]);
#pragma unroll
        for (int i = 0; i < 2; ++i)
            gl16(aptr[1][i] + kt, &sA[buf * 16384 + 8192 + (i * 512 + tid) * 8]);
#pragma unroll
        for (int i = 0; i < 2; ++i)
            gl16(bptr[i] + kt, &sB[buf * 8192 + (i * 512 + tid) * 8]);
    };

    // prologue: tiles 0 and 1 (12 loads); wait until tile 0's 6 done
    STAGE(0, 0);
    STAGE(1, 64);
    asm volatile("s_waitcnt vmcnt(6)" ::: "memory");
    __builtin_amdgcn_s_barrier();

    short8 af[8], bf[8];
    int rb = 0;

#pragma unroll 1
    for (int t = 0; t < NT; ++t) {
        const bool pf = (t + 2 < NT);
        int wb = rb + 2; if (wb >= 3) wb -= 3;
        const int cbA = rb * 16384, cbB = rb * 8192;

        // ---- LDS -> registers (16 x ds_read_b128) ----
#pragma unroll
        for (int m = 0; m < 4; ++m) {
            const int row = wr * 64 + m * 16 + lr;
#pragma unroll
            for (int kk = 0; kk < 2; ++kk)
                af[m * 2 + kk] = *(const short8*)&sA[cbA + (row << 6) + ((((kk << 2) + lk) ^ (row & 7)) << 3)];
        }
#pragma unroll
        for (int n = 0; n < 4; ++n) {
            const int row = wc * 64 + n * 16 + lr;
#pragma unroll
            for (int kk = 0; kk < 2; ++kk)
                bf[n * 2 + kk] = *(const short8*)&sB[cbB + (row << 6) + ((((kk << 2) + lk) ^ (row & 7)) << 3)];
        }

        // ---- issue stage of tile t+2 (2-tile prefetch distance) ----
        if (pf) STAGE(wb, (t + 2) * 64);

        // ---- 32 MFMA ----
        __builtin_amdgcn_s_setprio(1);
#pragma unroll
        for (int kk = 0; kk < 2; ++kk)
#pragma unroll
            for (int n = 0; n < 4; ++n)
#pragma unroll
                for (int m = 0; m < 4; ++m)
                    acc[m][n] = __builtin_amdgcn_mfma_f32_16x16x32_bf16(af[m * 2 + kk], bf[n * 2 + kk], acc[m][n], 0, 0, 0);
        __builtin_amdgcn_s_setprio(0);

        // ---- tile end: drain t-1's loads (buf[(t+1)%3] ready); keep t's in flight ----
        if (pf) asm volatile("s_waitcnt vmcnt(6)" ::: "memory");
        else    asm volatile("s_waitcnt vmcnt(0)" ::: "memory");
        __builtin_amdgcn_s_barrier();

        rb = (rb + 1 == 3) ? 0 : rb + 1;
    }

    // ---- epilogue ----
    if constexpr (UP) {
        const int hc0 = (n0 >> 1) + wc * 32 + lr;
        unsigned short* hb = (unsigned short*)outp;
#pragma unroll
        for (int m = 0; m < 4; ++m) {
#pragma unroll
            for (int j = 0; j < 4; ++j) {
                const int r = wr * 64 + m * 16 + lk * 4 + j;
                bool ok; size_t orow;
                if constexpr (MODE == 0) { ok = true; orow = (size_t)(r0 + r) * OSTR; }
                else { ok = (r0 + r < cnt); orow = (size_t)(gbase + r0 + r) * OSTR; }
                if (ok) {
                    float g0 = acc[m][0][j], u0 = acc[m][1][j];
                    float g1 = acc[m][2][j], u1 = acc[m][3][j];
                    hb[orow + hc0]      = f2bf(g0 / (1.f + __expf(-g0)) * u0);
                    hb[orow + hc0 + 16] = f2bf(g1 / (1.f + __expf(-g1)) * u1);
                }
            }
        }
    } else {
        float* op = (float*)outp;
#pragma unroll
        for (int m = 0; m < 4; ++m) {
#pragma unroll
            for (int j = 0; j < 4; ++j) {
                const int r = wr * 64 + m * 16 + lk * 4 + j;
                int tok; float scale; bool ok;
                if constexpr (MODE == 1) {
                    tok = r0 + r; scale = sg[tok]; ok = true;
                } else {
                    ok = (r0 + r < cnt);
                    int idx = ok ? (e * M_TOK + r0 + r) : (e * M_TOK);
                    tok = ltok[idx]; scale = lcoef[idx];
                }
                if (ok) {
                    size_t orow = (size_t)tok * H_DIM;
#pragma unroll
                    for (int n = 0; n < 4; ++n) {
                        const int col = n0 + wc * 64 + n * 16 + lr;
                        atomicAdd(op + orow + col, acc[m][n][j] * scale);
                    }
                }
            }
        }
    }
}

extern "C" void kernel_launch(void* const* d_in, const int* in_sizes, int n_in,
                              void* d_out, int out_size, void* d_ws, size_t ws_size,
                              hipStream_t stream) {
    const float* x    = (const float*)d_in[0];
    const float* gw   = (const float*)d_in[1];
    const float* sgw  = (const float*)d_in[2];
    const float* w13  = (const float*)d_in[3];
    const float* w2   = (const float*)d_in[4];
    const float* sguw = (const float*)d_in[5];
    const float* sdw  = (const float*)d_in[6];
    float* out = (float*)d_out;

    char* ws = (char*)d_ws;
    unsigned short* xb    = (unsigned short*)ws;                // 16,777,216 B
    unsigned short* hbuf  = (unsigned short*)(ws + 16777216);   // 46,137,344 B (hs then he)
    unsigned short* w13b  = (unsigned short*)(ws + 62914560);   // 184,549,376 B (permuted)
    unsigned short* w2b   = (unsigned short*)(ws + 247463936);  //  92,274,688 B
    unsigned short* sguwb = (unsigned short*)(ws + 339738624);  //  46,137,344 B (permuted)
    unsigned short* sdwb  = (unsigned short*)(ws + 385875968);  //  23,068,672 B
    size_t so = 408944640ULL;
    int*   ltok   = (int*)  (ws + so);
    float* lcoef  = (float*)(ws + so + 262144);
    int*   counts = (int*)  (ws + so + 524288);
    int*   basep  = (int*)  (ws + so + 524288 + 256);
    float* sg     = (float*)(ws + so + 524288 + 512);

    hipMemsetAsync(counts, 0, 64, stream);
    hipMemsetAsync(out, 0, (size_t)out_size * sizeof(float), stream);
    k_router<<<M_TOK / 4, 256, 0, stream>>>(x, gw, sgw, counts, ltok, lcoef, sg);
    k_prefix<<<1, 64, 0, stream>>>(counts, basep);
    k_cvtw<<<4096, 256, 0, stream>>>(x, xb, (size_t)M_TOK * H_DIM / 8);
    k_cvtp<2 * IS_DIM, IS_DIM><<<8192, 256, 0, stream>>>(sguw, sguwb, (size_t)2 * IS_DIM * H_DIM / 8);
    k_cvtw<<<8192, 256, 0, stream>>>(sdw,  sdwb,  (size_t)H_DIM * IS_DIM / 8);
    k_cvtp<2 * I_DIM, I_DIM><<<8192, 256, 0, stream>>>(w13, w13b, (size_t)E_NUM * 2 * I_DIM * H_DIM / 8);
    k_cvtw<<<8192, 256, 0, stream>>>(w2,   w2b,   (size_t)E_NUM * H_DIM * I_DIM / 8);

    static const int DYN = 147456;   // 3 x (32 KiB A + 16 KiB B)
    (void)hipFuncSetAttribute(reinterpret_cast<const void*>(&k_gemm<0, 2048, 0LL, 1>),
                              hipFuncAttributeMaxDynamicSharedMemorySize, DYN);
    (void)hipFuncSetAttribute(reinterpret_cast<const void*>(&k_gemm<1, 5632, 0LL, 2>),
                              hipFuncAttributeMaxDynamicSharedMemorySize, DYN);
    (void)hipFuncSetAttribute(reinterpret_cast<const void*>(&k_gemm<2, 2048, 5767168LL, 1>),
                              hipFuncAttributeMaxDynamicSharedMemorySize, DYN);
    (void)hipFuncSetAttribute(reinterpret_cast<const void*>(&k_gemm<3, 1408, 2883584LL, 1>),
                              hipFuncAttributeMaxDynamicSharedMemorySize, DYN);

    // shared up: xb[4096,2048] x sguwb^T -> silu-mul pairs -> hs bf16 [4096,5632]
    k_gemm<0, 2048, 0LL, 1>
        <<<dim3(2 * IS_DIM / 128, M_TOK / 256, 1), 512, DYN, stream>>>(
            xb, sguwb, hbuf, ltok, lcoef, counts, basep, sg);
    // shared down (split-K=2): hs x sdwb^T * sg -> atomicAdd out
    k_gemm<1, 5632, 0LL, 2>
        <<<dim3(H_DIM / 128, M_TOK / 256, 2), 512, DYN, stream>>>(
            hbuf, sdwb, out, ltok, lcoef, counts, basep, sg);
    // expert up (gathered): xb x w13b_e^T -> silu-mul -> he bf16 [16384,1408]
    k_gemm<2, 2048, 5767168LL, 1>
        <<<dim3(2 * I_DIM / 128, M_TOK / 256, E_NUM), 512, DYN, stream>>>(
            xb, w13b, hbuf, ltok, lcoef, counts, basep, sg);
    // expert down: he x w2b_e^T * coef -> atomicAdd out
    k_gemm<3, 1408, 2883584LL, 1>
        <<<dim3(H_DIM / 128, M_TOK / 256, E_NUM), 512, DYN, stream>>>(
            hbuf, w2b, out, ltok, lcoef, counts, basep, sg);
}